// Round 4
// baseline (490.259 us; speedup 1.0000x reference)
//
#include <hip/hip_runtime.h>
#include <math.h>
#include <stdint.h>

constexpr int N   = 50000;
constexpr int E   = 800000;
constexpr int IN  = 128;
constexpr int H   = 256;
constexpr int OUT = 10;
constexpr int G   = 512;
constexpr int BSTR = 64;   // bucket stride (max degree; Poisson(16) -> P(>64) ~ 1e-21)

typedef __bf16 bf16x8 __attribute__((ext_vector_type(8)));
typedef float  f32x4  __attribute__((ext_vector_type(4)));

__device__ __forceinline__ float blo(unsigned v) { return __uint_as_float(v << 16); }
__device__ __forceinline__ float bhi(unsigned v) { return __uint_as_float(v & 0xffff0000u); }
__device__ __forceinline__ unsigned short f2b(float f) {
  unsigned u = __float_as_uint(f);
  u += 0x7fffu + ((u >> 16) & 1u);   // RNE (no NaNs in this net)
  return (unsigned short)(u >> 16);
}
__device__ __forceinline__ unsigned packb(float lo, float hi) {
  return (unsigned)f2b(lo) | ((unsigned)f2b(hi) << 16);
}

// ---------------- bucket CSR: one pass, no scan ----------------

__global__ void fill_bucket_kernel(const int* __restrict__ src, const int* __restrict__ dst,
                                   int* __restrict__ deg, int* __restrict__ csre) {
  int e = blockIdx.x * blockDim.x + threadIdx.x;
  if (e >= E) return;
  int d = dst[e];
  int pos = atomicAdd(&deg[d], 1);
  if (pos < BSTR) csre[(size_t)d * BSTR + pos] = src[e];
}

// ---------------- fused fp32->bf16 conversions (x + 4 weight transposes) ----------------

constexpr int XB_BLOCKS  = (N * IN / 4) / 256;      // 6250 (exact)
constexpr int W1A_BLOCKS = (256 * IN) / 256;        // 128
constexpr int WH_BLOCKS  = (256 * H) / 256;         // 256

__global__ void prep_kernel(const float* __restrict__ x, unsigned short* __restrict__ xb,
                            const float* __restrict__ W1a, unsigned short* __restrict__ Wt1a,
                            const float* __restrict__ W1b, unsigned short* __restrict__ Wt1b,
                            const float* __restrict__ W2a, unsigned short* __restrict__ Wt2a,
                            const float* __restrict__ W2b, unsigned short* __restrict__ Wt2b) {
  int b = blockIdx.x;
  int t = threadIdx.x;
  if (b < XB_BLOCKS) {
    int id = b * 256 + t;
    float4 v = ((const float4*)x)[id];
    ((uint2*)xb)[id] = make_uint2(packb(v.x, v.y), packb(v.z, v.w));
    return;
  }
  b -= XB_BLOCKS;
  if (b < W1A_BLOCKS) {
    int id = b * 256 + t;               // id = n*128 + k
    int n = id >> 7, k = id & 127;
    Wt1a[id] = f2b(W1a[k * 256 + n]);
    return;
  }
  b -= W1A_BLOCKS;
  const float* Ws;
  unsigned short* Wd;
  if (b < WH_BLOCKS)            { Ws = W1b; Wd = Wt1b; }
  else if (b < 2 * WH_BLOCKS)   { Ws = W2a; Wd = Wt2a; b -= WH_BLOCKS; }
  else                          { Ws = W2b; Wd = Wt2b; b -= 2 * WH_BLOCKS; }
  int id = b * 256 + t;                 // id = n*256 + k
  int n = id >> 8, k = id & 255;
  Wd[id] = f2b(Ws[k * 256 + n]);
}

// ---------------- fused aggregate + GEMM-a ----------------
// out[i][:] = relu( [ (1+eps)*in[i] + sum_nbr in[j] ] @ Wt^T + bias ),  256 output cols.
// Block: 256 threads = 4 waves; tile = 64 rows x 256 cols.
// Phase 1: wave w gathers+aggregates rows [w*16, w*16+16) into LDS As (full K).
// Phase 2: K-loop, Bs chunk staged per 32-k, 4x4 MFMA 16x16x32 per wave (wave w -> cols w*64).

template <int K>
__global__ __launch_bounds__(256, 2) void agg_gemm_kernel(
    const unsigned short* __restrict__ Ain,   // [N][K] bf16
    const int* __restrict__ deg, const int* __restrict__ csre,
    const float* __restrict__ epsp,
    const unsigned short* __restrict__ Bt,    // [256][K] bf16 (pre-transposed)
    const float* __restrict__ bias,
    unsigned short* __restrict__ out) {       // [N][256] bf16
  constexpr int LDA = K + 8;                  // pad 8 units = 16 B (keeps 16B align)
  __shared__ __align__(16) unsigned short As[64 * LDA];
  __shared__ __align__(16) unsigned short Bs[256 * 40];
  const int tid  = threadIdx.x;
  const int r0   = blockIdx.x * 64;
  const int wave = tid >> 6, lane = tid & 63;
  const int quad = lane >> 4, l15 = lane & 15;
  const int wcol = wave * 64;
  const float sc = 1.0f + epsp[0];

  // ---- phase 1: gather + aggregate 16 rows per wave ----
  for (int rr = 0; rr < 16; ++rr) {
    int r = wave * 16 + rr;
    int gi = r0 + r;
    if constexpr (K == 128) {
      const unsigned* base = (const unsigned*)Ain;   // row stride 64 units
      float a0 = 0.f, a1 = 0.f;
      if (gi < N) {
        int dg = deg[gi]; if (dg > BSTR) dg = BSTR;
        const int* bkt = csre + (size_t)gi * BSTR;
        int j = 0;
        for (; j + 8 <= dg; j += 8) {
          int idx[8];
#pragma unroll
          for (int u = 0; u < 8; ++u) idx[u] = bkt[j + u];
          unsigned v[8];
#pragma unroll
          for (int u = 0; u < 8; ++u) v[u] = base[(size_t)idx[u] * 64 + lane];
#pragma unroll
          for (int u = 0; u < 8; ++u) { a0 += blo(v[u]); a1 += bhi(v[u]); }
        }
        for (; j < dg; ++j) {
          unsigned v = base[(size_t)bkt[j] * 64 + lane];
          a0 += blo(v); a1 += bhi(v);
        }
        unsigned sv = base[(size_t)gi * 64 + lane];
        a0 += sc * blo(sv); a1 += sc * bhi(sv);
      }
      *(unsigned*)(As + r * LDA + 2 * lane) = packb(a0, a1);
    } else {
      const uint2* base = (const uint2*)Ain;         // row stride 64 uint2
      float a0 = 0.f, a1 = 0.f, a2 = 0.f, a3 = 0.f;
      if (gi < N) {
        int dg = deg[gi]; if (dg > BSTR) dg = BSTR;
        const int* bkt = csre + (size_t)gi * BSTR;
        int j = 0;
        for (; j + 8 <= dg; j += 8) {
          int idx[8];
#pragma unroll
          for (int u = 0; u < 8; ++u) idx[u] = bkt[j + u];
          uint2 v[8];
#pragma unroll
          for (int u = 0; u < 8; ++u) v[u] = base[(size_t)idx[u] * 64 + lane];
#pragma unroll
          for (int u = 0; u < 8; ++u) {
            a0 += blo(v[u].x); a1 += bhi(v[u].x); a2 += blo(v[u].y); a3 += bhi(v[u].y);
          }
        }
        for (; j < dg; ++j) {
          uint2 v = base[(size_t)bkt[j] * 64 + lane];
          a0 += blo(v.x); a1 += bhi(v.x); a2 += blo(v.y); a3 += bhi(v.y);
        }
        uint2 sv = base[(size_t)gi * 64 + lane];
        a0 += sc * blo(sv.x); a1 += sc * bhi(sv.x); a2 += sc * blo(sv.y); a3 += sc * bhi(sv.y);
      }
      *(uint2*)(As + r * LDA + 4 * lane) = make_uint2(packb(a0, a1), packb(a2, a3));
    }
  }
  __syncthreads();

  // ---- phase 2: MFMA K-loop ----
  f32x4 acc[4][4];
#pragma unroll
  for (int i = 0; i < 4; ++i)
#pragma unroll
    for (int j = 0; j < 4; ++j) acc[i][j] = (f32x4){0.f, 0.f, 0.f, 0.f};

  for (int kc = 0; kc < K; kc += 32) {
    // stage Bs: 256 cols x 32 k, 4 rounds of uint4
#pragma unroll
    for (int rd = 0; rd < 4; ++rd) {
      int id = rd * 256 + tid;           // 0..1023
      int col = id >> 2, k8 = (id & 3) * 8;
      *(uint4*)(Bs + col * 40 + k8) = *(const uint4*)(Bt + (size_t)col * K + kc + k8);
    }
    __syncthreads();
    bf16x8 af[4], bfr[4];
#pragma unroll
    for (int mt = 0; mt < 4; ++mt)
      af[mt] = *(const bf16x8*)(As + (mt * 16 + l15) * LDA + kc + quad * 8);
#pragma unroll
    for (int nt = 0; nt < 4; ++nt)
      bfr[nt] = *(const bf16x8*)(Bs + (wcol + nt * 16 + l15) * 40 + quad * 8);
#pragma unroll
    for (int mt = 0; mt < 4; ++mt)
#pragma unroll
      for (int nt = 0; nt < 4; ++nt)
        acc[mt][nt] = __builtin_amdgcn_mfma_f32_16x16x32_bf16(af[mt], bfr[nt], acc[mt][nt], 0, 0, 0);
    __syncthreads();
  }

  float bv[4];
#pragma unroll
  for (int nt = 0; nt < 4; ++nt) bv[nt] = bias[wcol + nt * 16 + l15];
#pragma unroll
  for (int mt = 0; mt < 4; ++mt) {
    int gr0 = r0 + mt * 16 + quad * 4;
#pragma unroll
    for (int i = 0; i < 4; ++i) {
      int grow = gr0 + i;
      if (grow >= N) continue;
#pragma unroll
      for (int nt = 0; nt < 4; ++nt) {
        float v = fmaxf(acc[mt][nt][i] + bv[nt], 0.f);
        out[(size_t)grow * 256 + wcol + nt * 16 + l15] = f2b(v);
      }
    }
  }
}

// ---------------- bf16 MFMA GEMM (second MLP linear): out = act(A[N][256] @ W + b) ----------------
// unchanged proven structure: 128x128 tile, BK=32, 4 waves.

template <bool RELU>
__global__ __launch_bounds__(256, 2) void gemm_bf16_kernel(const unsigned short* __restrict__ A,
                                                           const unsigned short* __restrict__ Bt,
                                                           const float* __restrict__ bias,
                                                           unsigned short* __restrict__ out,
                                                           int Nrows) {
  constexpr int K = 256, M = 256, LDK = 40;
  __shared__ __align__(16) unsigned short As[128 * LDK];
  __shared__ __align__(16) unsigned short Bs[128 * LDK];
  const int tid  = threadIdx.x;
  const int r0   = blockIdx.x * 128;
  const int c0   = blockIdx.y * 128;
  const int wave = tid >> 6, lane = tid & 63;
  const int quad = lane >> 4, l15 = lane & 15;
  const int wrow = (wave >> 1) * 64, wcol = (wave & 1) * 64;
  const int srow = tid >> 2;
  const int sk8  = (tid & 3) * 8;

  f32x4 acc[4][4];
#pragma unroll
  for (int i = 0; i < 4; ++i)
#pragma unroll
    for (int j = 0; j < 4; ++j) acc[i][j] = (f32x4){0.f, 0.f, 0.f, 0.f};

  for (int k0 = 0; k0 < K; k0 += 32) {
    {
      int row = srow, grow = r0 + row;
      uint4 v = make_uint4(0u, 0u, 0u, 0u);
      if (grow < Nrows) v = *(const uint4*)(A + (size_t)grow * K + k0 + sk8);
      *(uint4*)(As + row * LDK + sk8) = v;
      row += 64; grow = r0 + row;
      uint4 w = make_uint4(0u, 0u, 0u, 0u);
      if (grow < Nrows) w = *(const uint4*)(A + (size_t)grow * K + k0 + sk8);
      *(uint4*)(As + row * LDK + sk8) = w;
      *(uint4*)(Bs + srow * LDK + sk8) =
          *(const uint4*)(Bt + (size_t)(c0 + srow) * K + k0 + sk8);
      *(uint4*)(Bs + (srow + 64) * LDK + sk8) =
          *(const uint4*)(Bt + (size_t)(c0 + srow + 64) * K + k0 + sk8);
    }
    __syncthreads();
    bf16x8 af[4], bfr[4];
#pragma unroll
    for (int mt = 0; mt < 4; ++mt)
      af[mt] = *(const bf16x8*)(As + (wrow + mt * 16 + l15) * LDK + quad * 8);
#pragma unroll
    for (int nt = 0; nt < 4; ++nt)
      bfr[nt] = *(const bf16x8*)(Bs + (wcol + nt * 16 + l15) * LDK + quad * 8);
#pragma unroll
    for (int mt = 0; mt < 4; ++mt)
#pragma unroll
      for (int nt = 0; nt < 4; ++nt)
        acc[mt][nt] = __builtin_amdgcn_mfma_f32_16x16x32_bf16(af[mt], bfr[nt], acc[mt][nt], 0, 0, 0);
    __syncthreads();
  }

  float bv[4];
#pragma unroll
  for (int nt = 0; nt < 4; ++nt) bv[nt] = bias[c0 + wcol + nt * 16 + l15];
#pragma unroll
  for (int mt = 0; mt < 4; ++mt) {
    int gr0 = r0 + wrow + mt * 16 + quad * 4;
#pragma unroll
    for (int i = 0; i < 4; ++i) {
      int grow = gr0 + i;
      if (grow >= Nrows) continue;
#pragma unroll
      for (int nt = 0; nt < 4; ++nt) {
        float v = acc[mt][nt][i] + bv[nt];
        if (RELU) v = fmaxf(v, 0.f);
        out[(size_t)grow * M + c0 + wcol + nt * 16 + l15] = f2b(v);
      }
    }
  }
}

// ---------------- fused mean-pool + classifier + log_softmax ----------------

__global__ __launch_bounds__(128) void pool_final_kernel(const unsigned short* __restrict__ h2,
                                                         const int* __restrict__ batch,
                                                         const float* __restrict__ Wlin,
                                                         const float* __restrict__ blin,
                                                         float* __restrict__ out) {
  __shared__ float sp[H];
  __shared__ float logits[OUT];
  int g = blockIdx.x;
  int t = threadIdx.x;  // 128, 2 cols each
  int lo = 0, hi = N;
  while (lo < hi) { int m = (lo + hi) >> 1; if (batch[m] < g) lo = m + 1; else hi = m; }
  int s = lo;
  lo = 0; hi = N;
  while (lo < hi) { int m = (lo + hi) >> 1; if (batch[m] < g + 1) lo = m + 1; else hi = m; }
  int e = lo;
  float a0 = 0.f, a1 = 0.f;
  const unsigned* base = (const unsigned*)h2;
  int n = s;
  for (; n + 4 <= e; n += 4) {
    unsigned v0 = base[(size_t)(n + 0) * (H / 2) + t];
    unsigned v1 = base[(size_t)(n + 1) * (H / 2) + t];
    unsigned v2 = base[(size_t)(n + 2) * (H / 2) + t];
    unsigned v3 = base[(size_t)(n + 3) * (H / 2) + t];
    a0 += blo(v0) + blo(v1) + blo(v2) + blo(v3);
    a1 += bhi(v0) + bhi(v1) + bhi(v2) + bhi(v3);
  }
  for (; n < e; ++n) {
    unsigned v = base[(size_t)n * (H / 2) + t];
    a0 += blo(v); a1 += bhi(v);
  }
  float inv = 1.0f / fmaxf((float)(e - s), 1.0f);
  sp[2 * t]     = a0 * inv;
  sp[2 * t + 1] = a1 * inv;
  __syncthreads();
  if (t < OUT) {
    float acc = blin[t];
    for (int k = 0; k < H; ++k) acc = fmaf(sp[k], Wlin[k * OUT + t], acc);
    logits[t] = acc;
  }
  __syncthreads();
  if (t == 0) {
    float m = -INFINITY;
    for (int j = 0; j < OUT; ++j) m = fmaxf(m, logits[j]);
    float ssum = 0.f;
    for (int j = 0; j < OUT; ++j) ssum += expf(logits[j] - m);
    float ls = logf(ssum);
    for (int j = 0; j < OUT; ++j) out[(size_t)g * OUT + j] = logits[j] - m - ls;
  }
}

// ---------------- launch ----------------

static inline char* align_up(char* p, size_t a) {
  return (char*)(((uintptr_t)p + a - 1) & ~(a - 1));
}

extern "C" void kernel_launch(void* const* d_in, const int* in_sizes, int n_in,
                              void* d_out, int out_size, void* d_ws, size_t ws_size,
                              hipStream_t stream) {
  const float* x    = (const float*)d_in[0];
  const int*   ei   = (const int*)d_in[1];
  const int*   srcp = ei;
  const int*   dstp = ei + E;
  const int*   batch = (const int*)d_in[2];
  const float* eps1 = (const float*)d_in[3];
  const float* W1a  = (const float*)d_in[4];
  const float* b1a  = (const float*)d_in[5];
  const float* W1b  = (const float*)d_in[6];
  const float* b1b  = (const float*)d_in[7];
  const float* eps2 = (const float*)d_in[8];
  const float* W2a  = (const float*)d_in[9];
  const float* b2a  = (const float*)d_in[10];
  const float* W2b  = (const float*)d_in[11];
  const float* b2b  = (const float*)d_in[12];
  const float* Wlin = (const float*)d_in[13];
  const float* blin = (const float*)d_in[14];
  float* outp = (float*)d_out;

  char* p = (char*)d_ws;
  int* deg  = (int*)p;               p = align_up(p + (size_t)N * 4, 256);
  int* csre = (int*)p;               p = align_up(p + (size_t)N * BSTR * 4, 256);
  unsigned short* xb   = (unsigned short*)p;  p = align_up(p + (size_t)N * IN * 2, 256);
  unsigned short* B1   = (unsigned short*)p;  p = align_up(p + (size_t)N * H * 2, 256);
  unsigned short* B2   = (unsigned short*)p;  p = align_up(p + (size_t)N * H * 2, 256);
  unsigned short* B3   = (unsigned short*)p;  p = align_up(p + (size_t)N * H * 2, 256);
  unsigned short* Wt1a = (unsigned short*)p;  p = align_up(p + (size_t)H * IN * 2, 256);
  unsigned short* Wt1b = (unsigned short*)p;  p = align_up(p + (size_t)H * H * 2, 256);
  unsigned short* Wt2a = (unsigned short*)p;  p = align_up(p + (size_t)H * H * 2, 256);
  unsigned short* Wt2b = (unsigned short*)p;  p = align_up(p + (size_t)H * H * 2, 256);

  hipMemsetAsync(deg, 0, (size_t)N * 4, stream);

  const int eblocks = (E + 255) / 256;
  fill_bucket_kernel<<<eblocks, 256, 0, stream>>>(srcp, dstp, deg, csre);

  prep_kernel<<<XB_BLOCKS + W1A_BLOCKS + 3 * WH_BLOCKS, 256, 0, stream>>>(
      x, xb, W1a, Wt1a, W1b, Wt1b, W2a, Wt2a, W2b, Wt2b);

  const int ablocks = (N + 63) / 64;   // 782
  const dim3 ggrid((N + 127) / 128, 2);

  // layer 1: fused agg+gemm1a, then gemm1b
  agg_gemm_kernel<IN><<<ablocks, 256, 0, stream>>>(xb, deg, csre, eps1, Wt1a, b1a, B1);
  gemm_bf16_kernel<true><<<ggrid, 256, 0, stream>>>(B1, Wt1b, b1b, B2, N);   // B2 = h1

  // layer 2: fused agg+gemm2a, then gemm2b
  agg_gemm_kernel<H><<<ablocks, 256, 0, stream>>>(B2, deg, csre, eps2, Wt2a, b2a, B1);
  gemm_bf16_kernel<false><<<ggrid, 256, 0, stream>>>(B1, Wt2b, b2b, B3, N);  // B3 = h2

  // pool + classify
  pool_final_kernel<<<G, 128, 0, stream>>>(B3, batch, Wlin, blin, outp);
}

// Round 5
// 338.486 us; speedup vs baseline: 1.4484x; 1.4484x over previous
//
#include <hip/hip_runtime.h>
#include <math.h>
#include <stdint.h>

constexpr int N   = 50000;
constexpr int E   = 800000;
constexpr int IN  = 128;
constexpr int H   = 256;
constexpr int OUT = 10;
constexpr int G   = 512;
constexpr int BSTR = 64;   // bucket stride (max degree; Poisson(16) -> P(>64) ~ 1e-21)

typedef __bf16 bf16x8 __attribute__((ext_vector_type(8)));
typedef float  f32x4  __attribute__((ext_vector_type(4)));

__device__ __forceinline__ float blo(unsigned v) { return __uint_as_float(v << 16); }
__device__ __forceinline__ float bhi(unsigned v) { return __uint_as_float(v & 0xffff0000u); }
__device__ __forceinline__ unsigned short f2b(float f) {
  unsigned u = __float_as_uint(f);
  u += 0x7fffu + ((u >> 16) & 1u);   // RNE (no NaNs in this net)
  return (unsigned short)(u >> 16);
}
__device__ __forceinline__ unsigned packb(float lo, float hi) {
  return (unsigned)f2b(lo) | ((unsigned)f2b(hi) << 16);
}

// ---------------- prep: zero deg + fp32->bf16 conversions (x + 4 weight transposes) ----------------

constexpr int Z_BLOCKS   = (N + 255) / 256;         // 196
constexpr int XB_BLOCKS  = (N * IN / 4) / 256;      // 6250 (exact)
constexpr int W1A_BLOCKS = (256 * IN) / 256;        // 128
constexpr int WH_BLOCKS  = (256 * H) / 256;         // 256

__global__ void prep_kernel(int* __restrict__ deg,
                            const float* __restrict__ x, unsigned short* __restrict__ xb,
                            const float* __restrict__ W1a, unsigned short* __restrict__ Wt1a,
                            const float* __restrict__ W1b, unsigned short* __restrict__ Wt1b,
                            const float* __restrict__ W2a, unsigned short* __restrict__ Wt2a,
                            const float* __restrict__ W2b, unsigned short* __restrict__ Wt2b) {
  int b = blockIdx.x;
  int t = threadIdx.x;
  if (b < Z_BLOCKS) {
    int id = b * 256 + t;
    if (id < N) deg[id] = 0;
    return;
  }
  b -= Z_BLOCKS;
  if (b < XB_BLOCKS) {
    int id = b * 256 + t;
    float4 v = ((const float4*)x)[id];
    ((uint2*)xb)[id] = make_uint2(packb(v.x, v.y), packb(v.z, v.w));
    return;
  }
  b -= XB_BLOCKS;
  if (b < W1A_BLOCKS) {
    int id = b * 256 + t;               // id = n*128 + k
    int n = id >> 7, k = id & 127;
    Wt1a[id] = f2b(W1a[k * 256 + n]);
    return;
  }
  b -= W1A_BLOCKS;
  const float* Ws;
  unsigned short* Wd;
  if (b < WH_BLOCKS)            { Ws = W1b; Wd = Wt1b; }
  else if (b < 2 * WH_BLOCKS)   { Ws = W2a; Wd = Wt2a; b -= WH_BLOCKS; }
  else                          { Ws = W2b; Wd = Wt2b; b -= 2 * WH_BLOCKS; }
  int id = b * 256 + t;                 // id = n*256 + k
  int n = id >> 8, k = id & 255;
  Wd[id] = f2b(Ws[k * 256 + n]);
}

// ---------------- bucket CSR: one pass, no scan ----------------

__global__ void fill_bucket_kernel(const int* __restrict__ src, const int* __restrict__ dst,
                                   int* __restrict__ deg, int* __restrict__ csre) {
  int e = blockIdx.x * blockDim.x + threadIdx.x;
  if (e >= E) return;
  int d = dst[e];
  int pos = atomicAdd(&deg[d], 1);
  if (pos < BSTR) csre[(size_t)d * BSTR + pos] = src[e];
}

// ---------------- agg layer 1 (D=128): out[i] = (1+eps)*in[i] + sum_nbr in[j] ----------------
// one wave per node, uint2 (4 cols) per lane, 8-deep gather MLP.

__global__ __launch_bounds__(64) void agg1_kernel(const unsigned short* __restrict__ in,
                                                  const int* __restrict__ deg,
                                                  const int* __restrict__ csre,
                                                  const float* __restrict__ epsp,
                                                  unsigned short* __restrict__ out) {
  int i = blockIdx.x;
  int t = threadIdx.x;
  int dg = deg[i]; if (dg > BSTR) dg = BSTR;
  const int* bkt = csre + (size_t)i * BSTR;
  float sc = 1.0f + epsp[0];
  const unsigned* base = (const unsigned*)in;   // row stride 64 uints
  float a0 = 0.f, a1 = 0.f;
  int j = 0;
  for (; j + 8 <= dg; j += 8) {
    int idx[8];
#pragma unroll
    for (int u = 0; u < 8; ++u) idx[u] = bkt[j + u];
    unsigned v[8];
#pragma unroll
    for (int u = 0; u < 8; ++u) v[u] = base[(size_t)idx[u] * 64 + t];
#pragma unroll
    for (int u = 0; u < 8; ++u) { a0 += blo(v[u]); a1 += bhi(v[u]); }
  }
  for (; j < dg; ++j) {
    unsigned v = base[(size_t)bkt[j] * 64 + t];
    a0 += blo(v); a1 += bhi(v);
  }
  unsigned sv = base[(size_t)i * 64 + t];
  a0 += sc * blo(sv); a1 += sc * bhi(sv);
  ((unsigned*)out)[(size_t)i * 64 + t] = packb(a0, a1);
}

// ---------------- agg layer 2 (D=256) split-D: two half-column passes ----------------
// grid = 2N blocks; blocks [0,N) do cols [0,128), blocks [N,2N) cols [128,256).
// x-major issue order temporally separates the halves -> 12.8 MB working set per phase.

__global__ __launch_bounds__(64) void agg2_kernel(const unsigned short* __restrict__ in,
                                                  const int* __restrict__ deg,
                                                  const int* __restrict__ csre,
                                                  const float* __restrict__ epsp,
                                                  unsigned short* __restrict__ out) {
  int bx = blockIdx.x;
  int half = (bx >= N) ? 1 : 0;
  int i = bx - half * N;
  int t = threadIdx.x;
  int off = half * 64 + t;                      // uint index within row (row = 128 uints)
  int dg = deg[i]; if (dg > BSTR) dg = BSTR;
  const int* bkt = csre + (size_t)i * BSTR;
  float sc = 1.0f + epsp[0];
  const unsigned* base = (const unsigned*)in;   // row stride 128 uints
  float a0 = 0.f, a1 = 0.f;
  int j = 0;
  for (; j + 8 <= dg; j += 8) {
    int idx[8];
#pragma unroll
    for (int u = 0; u < 8; ++u) idx[u] = bkt[j + u];
    unsigned v[8];
#pragma unroll
    for (int u = 0; u < 8; ++u) v[u] = base[(size_t)idx[u] * 128 + off];
#pragma unroll
    for (int u = 0; u < 8; ++u) { a0 += blo(v[u]); a1 += bhi(v[u]); }
  }
  for (; j < dg; ++j) {
    unsigned v = base[(size_t)bkt[j] * 128 + off];
    a0 += blo(v); a1 += bhi(v);
  }
  unsigned sv = base[(size_t)i * 128 + off];
  a0 += sc * blo(sv); a1 += sc * bhi(sv);
  ((unsigned*)out)[(size_t)i * 128 + off] = packb(a0, a1);
}

// ---------------- bf16 MFMA GEMM: out[N][256] = act(A[N][K] @ W + b) ----------------
// proven structure: 128x128 tile, BK=32, 4 waves, LDK=40 (0 conflicts).

template <int K, bool RELU>
__global__ __launch_bounds__(256, 2) void gemm_bf16_kernel(const unsigned short* __restrict__ A,
                                                           const unsigned short* __restrict__ Bt,
                                                           const float* __restrict__ bias,
                                                           unsigned short* __restrict__ out,
                                                           int Nrows) {
  constexpr int M = 256, LDK = 40;
  __shared__ __align__(16) unsigned short As[128 * LDK];
  __shared__ __align__(16) unsigned short Bs[128 * LDK];
  const int tid  = threadIdx.x;
  const int r0   = blockIdx.x * 128;
  const int c0   = blockIdx.y * 128;
  const int wave = tid >> 6, lane = tid & 63;
  const int quad = lane >> 4, l15 = lane & 15;
  const int wrow = (wave >> 1) * 64, wcol = (wave & 1) * 64;
  const int srow = tid >> 2;
  const int sk8  = (tid & 3) * 8;

  f32x4 acc[4][4];
#pragma unroll
  for (int i = 0; i < 4; ++i)
#pragma unroll
    for (int j = 0; j < 4; ++j) acc[i][j] = (f32x4){0.f, 0.f, 0.f, 0.f};

  for (int k0 = 0; k0 < K; k0 += 32) {
    {
      int row = srow, grow = r0 + row;
      uint4 v = make_uint4(0u, 0u, 0u, 0u);
      if (grow < Nrows) v = *(const uint4*)(A + (size_t)grow * K + k0 + sk8);
      *(uint4*)(As + row * LDK + sk8) = v;
      row += 64; grow = r0 + row;
      uint4 w = make_uint4(0u, 0u, 0u, 0u);
      if (grow < Nrows) w = *(const uint4*)(A + (size_t)grow * K + k0 + sk8);
      *(uint4*)(As + row * LDK + sk8) = w;
      *(uint4*)(Bs + srow * LDK + sk8) =
          *(const uint4*)(Bt + (size_t)(c0 + srow) * K + k0 + sk8);
      *(uint4*)(Bs + (srow + 64) * LDK + sk8) =
          *(const uint4*)(Bt + (size_t)(c0 + srow + 64) * K + k0 + sk8);
    }
    __syncthreads();
    bf16x8 af[4], bfr[4];
#pragma unroll
    for (int mt = 0; mt < 4; ++mt)
      af[mt] = *(const bf16x8*)(As + (wrow + mt * 16 + l15) * LDK + quad * 8);
#pragma unroll
    for (int nt = 0; nt < 4; ++nt)
      bfr[nt] = *(const bf16x8*)(Bs + (wcol + nt * 16 + l15) * LDK + quad * 8);
#pragma unroll
    for (int mt = 0; mt < 4; ++mt)
#pragma unroll
      for (int nt = 0; nt < 4; ++nt)
        acc[mt][nt] = __builtin_amdgcn_mfma_f32_16x16x32_bf16(af[mt], bfr[nt], acc[mt][nt], 0, 0, 0);
    __syncthreads();
  }

  float bv[4];
#pragma unroll
  for (int nt = 0; nt < 4; ++nt) bv[nt] = bias[c0 + wcol + nt * 16 + l15];
#pragma unroll
  for (int mt = 0; mt < 4; ++mt) {
    int gr0 = r0 + wrow + mt * 16 + quad * 4;
#pragma unroll
    for (int i = 0; i < 4; ++i) {
      int grow = gr0 + i;
      if (grow >= Nrows) continue;
#pragma unroll
      for (int nt = 0; nt < 4; ++nt) {
        float v = acc[mt][nt][i] + bv[nt];
        if (RELU) v = fmaxf(v, 0.f);
        out[(size_t)grow * M + c0 + wcol + nt * 16 + l15] = f2b(v);
      }
    }
  }
}

// ---------------- fused mean-pool + classifier + log_softmax ----------------

__global__ __launch_bounds__(128) void pool_final_kernel(const unsigned short* __restrict__ h2,
                                                         const int* __restrict__ batch,
                                                         const float* __restrict__ Wlin,
                                                         const float* __restrict__ blin,
                                                         float* __restrict__ out) {
  __shared__ float sp[H];
  __shared__ float logits[OUT];
  int g = blockIdx.x;
  int t = threadIdx.x;  // 128, 2 cols each
  int lo = 0, hi = N;
  while (lo < hi) { int m = (lo + hi) >> 1; if (batch[m] < g) lo = m + 1; else hi = m; }
  int s = lo;
  lo = 0; hi = N;
  while (lo < hi) { int m = (lo + hi) >> 1; if (batch[m] < g + 1) lo = m + 1; else hi = m; }
  int e = lo;
  float a0 = 0.f, a1 = 0.f;
  const unsigned* base = (const unsigned*)h2;
  int n = s;
  for (; n + 4 <= e; n += 4) {
    unsigned v0 = base[(size_t)(n + 0) * (H / 2) + t];
    unsigned v1 = base[(size_t)(n + 1) * (H / 2) + t];
    unsigned v2 = base[(size_t)(n + 2) * (H / 2) + t];
    unsigned v3 = base[(size_t)(n + 3) * (H / 2) + t];
    a0 += blo(v0) + blo(v1) + blo(v2) + blo(v3);
    a1 += bhi(v0) + bhi(v1) + bhi(v2) + bhi(v3);
  }
  for (; n < e; ++n) {
    unsigned v = base[(size_t)n * (H / 2) + t];
    a0 += blo(v); a1 += bhi(v);
  }
  float inv = 1.0f / fmaxf((float)(e - s), 1.0f);
  sp[2 * t]     = a0 * inv;
  sp[2 * t + 1] = a1 * inv;
  __syncthreads();
  if (t < OUT) {
    float acc = blin[t];
    for (int k = 0; k < H; ++k) acc = fmaf(sp[k], Wlin[k * OUT + t], acc);
    logits[t] = acc;
  }
  __syncthreads();
  if (t == 0) {
    float m = -INFINITY;
    for (int j = 0; j < OUT; ++j) m = fmaxf(m, logits[j]);
    float ssum = 0.f;
    for (int j = 0; j < OUT; ++j) ssum += expf(logits[j] - m);
    float ls = logf(ssum);
    for (int j = 0; j < OUT; ++j) out[(size_t)g * OUT + j] = logits[j] - m - ls;
  }
}

// ---------------- launch ----------------

static inline char* align_up(char* p, size_t a) {
  return (char*)(((uintptr_t)p + a - 1) & ~(a - 1));
}

extern "C" void kernel_launch(void* const* d_in, const int* in_sizes, int n_in,
                              void* d_out, int out_size, void* d_ws, size_t ws_size,
                              hipStream_t stream) {
  const float* x    = (const float*)d_in[0];
  const int*   ei   = (const int*)d_in[1];
  const int*   srcp = ei;
  const int*   dstp = ei + E;
  const int*   batch = (const int*)d_in[2];
  const float* eps1 = (const float*)d_in[3];
  const float* W1a  = (const float*)d_in[4];
  const float* b1a  = (const float*)d_in[5];
  const float* W1b  = (const float*)d_in[6];
  const float* b1b  = (const float*)d_in[7];
  const float* eps2 = (const float*)d_in[8];
  const float* W2a  = (const float*)d_in[9];
  const float* b2a  = (const float*)d_in[10];
  const float* W2b  = (const float*)d_in[11];
  const float* b2b  = (const float*)d_in[12];
  const float* Wlin = (const float*)d_in[13];
  const float* blin = (const float*)d_in[14];
  float* outp = (float*)d_out;

  char* p = (char*)d_ws;
  int* deg  = (int*)p;               p = align_up(p + (size_t)N * 4, 256);
  int* csre = (int*)p;               p = align_up(p + (size_t)N * BSTR * 4, 256);
  unsigned short* xb   = (unsigned short*)p;  p = align_up(p + (size_t)N * IN * 2, 256);
  unsigned short* B1   = (unsigned short*)p;  p = align_up(p + (size_t)N * H * 2, 256);
  unsigned short* B2   = (unsigned short*)p;  p = align_up(p + (size_t)N * H * 2, 256);
  unsigned short* B3   = (unsigned short*)p;  p = align_up(p + (size_t)N * H * 2, 256);
  unsigned short* Wt1a = (unsigned short*)p;  p = align_up(p + (size_t)H * IN * 2, 256);
  unsigned short* Wt1b = (unsigned short*)p;  p = align_up(p + (size_t)H * H * 2, 256);
  unsigned short* Wt2a = (unsigned short*)p;  p = align_up(p + (size_t)H * H * 2, 256);
  unsigned short* Wt2b = (unsigned short*)p;  p = align_up(p + (size_t)H * H * 2, 256);

  // 1: prep (zero deg + bf16 conversions + weight transposes)
  prep_kernel<<<Z_BLOCKS + XB_BLOCKS + W1A_BLOCKS + 3 * WH_BLOCKS, 256, 0, stream>>>(
      deg, x, xb, W1a, Wt1a, W1b, Wt1b, W2a, Wt2a, W2b, Wt2b);

  // 2: bucket CSR
  fill_bucket_kernel<<<(E + 255) / 256, 256, 0, stream>>>(srcp, dstp, deg, csre);

  const dim3 ggrid((N + 127) / 128, 2);

  // layer 1
  agg1_kernel<<<N, 64, 0, stream>>>(xb, deg, csre, eps1, B1);
  gemm_bf16_kernel<IN, true><<<ggrid, 256, 0, stream>>>(B1, Wt1a, b1a, B2, N);
  gemm_bf16_kernel<H, true><<<ggrid, 256, 0, stream>>>(B2, Wt1b, b1b, B3, N);   // B3 = h1

  // layer 2
  agg2_kernel<<<2 * N, 64, 0, stream>>>(B3, deg, csre, eps2, B1);
  gemm_bf16_kernel<H, true><<<ggrid, 256, 0, stream>>>(B1, Wt2a, b2a, B2, N);
  gemm_bf16_kernel<H, false><<<ggrid, 256, 0, stream>>>(B2, Wt2b, b2b, B1, N);  // B1 = h2

  // pool + classify
  pool_final_kernel<<<G, 128, 0, stream>>>(B1, batch, Wlin, blin, outp);
}